// Round 9
// baseline (597.352 us; speedup 1.0000x reference)
//
#include <hip/hip_runtime.h>

#define N_NODES 100000
#define N_EDGES 1600000
#define D_IN    256
#define D_HID   64
#define D_OUT   32
#define NPROP   10

#define NBUCK 196          // bucket = row >> 9 (512 rows/bucket)
#define CHUNK 6080         // edges per bscatter block (LDS-limited)
#define NCHUNK ((N_EDGES + CHUNK - 1) / CHUNK)   // 264

#define MLP_BLOCKS 1563    // ceil(6250 waves / 4)
#define MLP_A 700          // slice sizes: D1 / D2 / D3
#define MLP_B 500
#define MLP_C (MLP_BLOCKS - MLP_A - MLP_B)   // 363

#define SPMM_BLOCKS 2048   // exactly-resident grid; grid-stride over 800000 units

typedef _Float16 half_t;
typedef _Float16 h8  __attribute__((ext_vector_type(8)));
typedef _Float16 h4  __attribute__((ext_vector_type(4)));
typedef float    f4v __attribute__((ext_vector_type(4)));
typedef int      i2v __attribute__((ext_vector_type(2)));

// ==================== MLP body (round-6 code, as device fn) ====================
#define HSTRIDE 72
#define MLP_LDS_BYTES (4 * 16 * HSTRIDE * 2 + 4 * 16 * 32 * 2)   // 13312

static __device__ __forceinline__ void mlp_body(
    int mb, int t, char* smem,
    const float* __restrict__ F, const half_t* __restrict__ W1T,
    const float* __restrict__ b1, const half_t* __restrict__ W2T,
    const float* __restrict__ b2, half_t* __restrict__ x0h)
{
  half_t* h_lds   = (half_t*)smem;                       // 4*16*72
  half_t* out_lds = (half_t*)(smem + 4 * 16 * HSTRIDE * 2);  // 4*16*32
  int w = t >> 6, lane = t & 63;
  int m = lane & 15, q = lane >> 4;
  int gw = mb * 4 + w;
  int node0 = gw * 16;
  if (node0 > N_NODES - 16) node0 = N_NODES - 16;  // tail waves duplicate last tile

  const float* ap = F + (size_t)(node0 + m) * D_IN + q * 8;
  float4 fr[16];
#pragma unroll
  for (int s = 0; s < 8; ++s) {
    fr[2 * s]     = *(const float4*)(ap + s * 32);
    fr[2 * s + 1] = *(const float4*)(ap + s * 32 + 4);
  }

  h8 af[8];
#pragma unroll
  for (int s = 0; s < 8; ++s) {
    float4 f0 = fr[2 * s], f1 = fr[2 * s + 1];
    h8 a;
    a[0] = (_Float16)f0.x; a[1] = (_Float16)f0.y;
    a[2] = (_Float16)f0.z; a[3] = (_Float16)f0.w;
    a[4] = (_Float16)f1.x; a[5] = (_Float16)f1.y;
    a[6] = (_Float16)f1.z; a[7] = (_Float16)f1.w;
    af[s] = a;
  }

  f4v acc[4];
#pragma unroll
  for (int i = 0; i < 4; ++i) acc[i] = (f4v){0.f, 0.f, 0.f, 0.f};
  const half_t* bp = W1T + (size_t)m * D_IN + q * 8;
#pragma unroll
  for (int s = 0; s < 8; ++s) {
    h8 b0 = *(const h8*)(bp + 0 * 16 * D_IN + s * 32);
    h8 b1v = *(const h8*)(bp + 1 * 16 * D_IN + s * 32);
    h8 b2v = *(const h8*)(bp + 2 * 16 * D_IN + s * 32);
    h8 b3v = *(const h8*)(bp + 3 * 16 * D_IN + s * 32);
    acc[0] = __builtin_amdgcn_mfma_f32_16x16x32_f16(af[s], b0, acc[0], 0, 0, 0);
    acc[1] = __builtin_amdgcn_mfma_f32_16x16x32_f16(af[s], b1v, acc[1], 0, 0, 0);
    acc[2] = __builtin_amdgcn_mfma_f32_16x16x32_f16(af[s], b2v, acc[2], 0, 0, 0);
    acc[3] = __builtin_amdgcn_mfma_f32_16x16x32_f16(af[s], b3v, acc[3], 0, 0, 0);
  }

  half_t* hw = h_lds + w * 16 * HSTRIDE;
#pragma unroll
  for (int ht = 0; ht < 4; ++ht) {
    float bb = b1[ht * 16 + m];
#pragma unroll
    for (int i = 0; i < 4; ++i) {
      float hv = fmaxf(acc[ht][i] + bb, 0.f);
      hw[(q * 4 + i) * HSTRIDE + ht * 16 + m] = (half_t)hv;
    }
  }
  __syncthreads();

  f4v o0 = {0.f, 0.f, 0.f, 0.f}, o1 = {0.f, 0.f, 0.f, 0.f};
#pragma unroll
  for (int s = 0; s < 2; ++s) {
    h8 a = *(const h8*)(hw + m * HSTRIDE + s * 32 + q * 8);
    h8 bb0 = *(const h8*)(W2T + (size_t)m * D_HID + s * 32 + q * 8);
    h8 bb1 = *(const h8*)(W2T + (size_t)(16 + m) * D_HID + s * 32 + q * 8);
    o0 = __builtin_amdgcn_mfma_f32_16x16x32_f16(a, bb0, o0, 0, 0, 0);
    o1 = __builtin_amdgcn_mfma_f32_16x16x32_f16(a, bb1, o1, 0, 0, 0);
  }
  half_t* ow = out_lds + w * 16 * 32;
  {
    float c0 = b2[m], c1 = b2[16 + m];
#pragma unroll
    for (int i = 0; i < 4; ++i) {
      ow[(q * 4 + i) * 32 + m]      = (half_t)(o0[i] + c0);
      ow[(q * 4 + i) * 32 + 16 + m] = (half_t)(o1[i] + c1);
    }
  }
  __syncthreads();

  {
    int nl = lane >> 2, qq = lane & 3;
    *(int4*)(x0h + (size_t)(node0 + nl) * D_OUT + qq * 8) =
        *(const int4*)(ow + nl * 32 + qq * 8);
  }
}

// ==================== D0: bhist (b<640) + weight pack (b>=640) ====================
__global__ __launch_bounds__(256) void mix0_kernel(
    const int* __restrict__ row, int* __restrict__ bcnt,
    const float* __restrict__ W1, const float* __restrict__ W2,
    half_t* __restrict__ W1T, half_t* __restrict__ W2T)
{
  __shared__ int lb[NBUCK];
  int b = blockIdx.x, t = threadIdx.x;
  if (b < 640) {
    for (int i = t; i < NBUCK; i += 256) lb[i] = 0;
    __syncthreads();
    const int stride = 640 * 256;
    for (int e = b * 256 + t; e < N_EDGES; e += stride)
      atomicAdd(&lb[row[e] >> 9], 1);
    __syncthreads();
    for (int i = t; i < NBUCK; i += 256)
      if (lb[i]) atomicAdd(&bcnt[i], lb[i]);
  } else {
    int g = (b - 640) * 256 + t;
    if (g < 64 * 256) { int n = g >> 8, k = g & 255; W1T[g] = (half_t)W1[k * 64 + n]; }
    if (g < 32 * 64)  { int n = g >> 6, k = g & 63;  W2T[g] = (half_t)W2[k * 32 + n]; }
  }
}

// ==================== D1: bscan (b==0) + mlp slice A ====================
__global__ __launch_bounds__(256, 2) void mix1_kernel(
    const int* __restrict__ bcnt, int* __restrict__ bbase, int* __restrict__ pbase,
    const float* __restrict__ F, const half_t* __restrict__ W1T,
    const float* __restrict__ b1, const half_t* __restrict__ W2T,
    const float* __restrict__ b2, half_t* __restrict__ x0h)
{
  __shared__ __align__(16) char smem[MLP_LDS_BYTES];   // mlp needs 13312; bscan 2KB
  int b = blockIdx.x, t = threadIdx.x;
  if (b == 0) {
    int* l1 = (int*)smem;           // 256 ints
    int* l2 = (int*)smem + 256;     // 256 ints
    int a = (t < NBUCK) ? bcnt[t] : 0;
    int r = (t < NBUCK) ? (((a + 3) & ~3) + 3 * 512) : 0;
    l1[t] = a; l2[t] = r;
    __syncthreads();
    for (int off = 1; off < 256; off <<= 1) {
      int x1 = (t >= off) ? l1[t - off] : 0;
      int x2 = (t >= off) ? l2[t - off] : 0;
      __syncthreads();
      l1[t] += x1; l2[t] += x2;
      __syncthreads();
    }
    if (t < NBUCK) { bbase[t] = l1[t] - a; pbase[t] = l2[t] - r; }
    if (t == NBUCK - 1) { bbase[NBUCK] = l1[t]; pbase[NBUCK] = l2[t]; }
  } else {
    mlp_body(b - 1, t, smem, F, W1T, b1, W2T, b2, x0h);
  }
}

// ==================== D2: bscatter (b<264) + mlp slice B ====================
__global__ __launch_bounds__(256, 2) void mix2_kernel(
    const int* __restrict__ row, const int* __restrict__ col,
    const float* __restrict__ vals, int* __restrict__ bfill,
    const int* __restrict__ bbase, int2* __restrict__ ebuck,
    const float* __restrict__ F, const half_t* __restrict__ W1T,
    const float* __restrict__ b1, const half_t* __restrict__ W2T,
    const float* __restrict__ b2, half_t* __restrict__ x0h)
{
  __shared__ int2 img[CHUNK];
  __shared__ unsigned short sbk[CHUNK];
  __shared__ int cnt[NBUCK], base[NBUCK], gb[NBUCK], fil[NBUCK];
  __shared__ int ssc[256];
  __shared__ __align__(16) char smem[MLP_LDS_BYTES];
  int b = blockIdx.x, t = threadIdx.x;

  if (b < NCHUNK) {
    int e0 = b * CHUNK;
    int n = min(CHUNK, N_EDGES - e0);

    for (int i = t; i < NBUCK; i += 256) { cnt[i] = 0; fil[i] = 0; }
    __syncthreads();
    for (int i = t; i < n; i += 256) atomicAdd(&cnt[row[e0 + i] >> 9], 1);
    __syncthreads();
    int c = (t < NBUCK) ? cnt[t] : 0;
    ssc[t] = c;
    __syncthreads();
    for (int off = 1; off < 256; off <<= 1) {
      int add = (t >= off) ? ssc[t - off] : 0;
      __syncthreads();
      ssc[t] += add;
      __syncthreads();
    }
    if (t < NBUCK) {
      base[t] = ssc[t] - c;
      gb[t] = c ? atomicAdd(&bfill[t], c) : 0;
    }
    __syncthreads();
    for (int i = t; i < n; i += 256) {
      int r = row[e0 + i];
      int bk = r >> 9;
      int p = base[bk] + atomicAdd(&fil[bk], 1);
      img[p] = make_int2(col[e0 + i] | ((r & 511) << 17),
                         __float_as_int(vals[e0 + i]));
      sbk[p] = (unsigned short)bk;
    }
    __syncthreads();
    for (int i = t; i < n; i += 256) {
      int bk = sbk[i];
      ebuck[bbase[bk] + gb[bk] + (i - base[bk])] = img[i];
    }
  } else {
    mlp_body(MLP_A + (b - NCHUNK), t, smem, F, W1T, b1, W2T, b2, x0h);
  }
}

// ==================== D3: bsort (b<196) + mlp slice C ====================
__global__ __launch_bounds__(256, 2) void mix3_kernel(
    const int* __restrict__ bbase, const int* __restrict__ pbase,
    const int2* __restrict__ ebuck, int2* __restrict__ epack,
    int* __restrict__ row_ptr,
    const float* __restrict__ F, const half_t* __restrict__ W1T,
    const float* __restrict__ b1, const half_t* __restrict__ W2T,
    const float* __restrict__ b2, half_t* __restrict__ x0h)
{
  __shared__ int acnt[512], loff[513], lfill[512], ssc[256];
  __shared__ __align__(16) char smem[MLP_LDS_BYTES];
  int b = blockIdx.x, t = threadIdx.x;

  if (b < NBUCK) {
    int r0 = b * 512;
    int nr = min(512, N_NODES - r0);
    int eb = bbase[b];
    int ne = bbase[b + 1] - eb;
    int pb = pbase[b];

    acnt[t] = 0; acnt[t + 256] = 0;
    lfill[t] = 0; lfill[t + 256] = 0;
    __syncthreads();
    for (int i = t; i < ne; i += 256)
      atomicAdd(&acnt[((unsigned)ebuck[eb + i].x) >> 17], 1);
    __syncthreads();
    int i0 = 2 * t, i1 = 2 * t + 1;
    int a0 = acnt[i0], a1 = acnt[i1];
    int p0 = (a0 + 3) & ~3, p1 = (a1 + 3) & ~3;
    int s = p0 + p1;
    ssc[t] = s;
    __syncthreads();
    for (int off = 1; off < 256; off <<= 1) {
      int add = (t >= off) ? ssc[t - off] : 0;
      __syncthreads();
      ssc[t] += add;
      __syncthreads();
    }
    int ex = ssc[t] - s;
    loff[i0] = ex;
    loff[i1] = ex + p0;
    if (t == 255) loff[512] = ssc[255];
    __syncthreads();
    int T = ssc[255];
    int slack = (pbase[b + 1] - pb) - T;
    int units = min(slack >> 2, nr);
    if (i0 < nr) row_ptr[r0 + i0] = pb + loff[i0] + 4 * min(i0, units);
    if (i1 < nr) row_ptr[r0 + i1] = pb + loff[i1] + 4 * min(i1, units);
    if (b == NBUCK - 1 && t == 0)
      row_ptr[N_NODES] = pb + loff[nr] + 4 * units;
    __syncthreads();
    for (int i = t; i < ne; i += 256) {
      int2 ed = ebuck[eb + i];
      int lr = ((unsigned)ed.x) >> 17;
      int cl = ed.x & 0x1FFFF;
      int p = loff[lr] + 4 * min(lr, units) + atomicAdd(&lfill[lr], 1);
      epack[pb + p] = make_int2(cl, ed.y);
    }
    __syncthreads();
    for (int i = t; i < nr; i += 256) {
      int a = acnt[i];
      int size_i = ((a + 3) & ~3) + 4 * (i < units);
      int st = loff[i] + 4 * min(i, units);
      for (int p = st + a; p < st + size_i; ++p)
        epack[pb + p] = make_int2(0, 0);
    }
  } else {
    mlp_body(MLP_A + MLP_B + (b - NBUCK), t, smem, F, W1T, b1, W2T, b2, x0h);
  }
}

// ==================== propagation (round-8 + NT on ep loads ONLY) ==========
// epack is a 14 MB/round zero-reuse stream (each line read once, lanes
// broadcast-coalesced); cached normally it cycles the 4 MB/XCD L2 3.5x per
// round and evicts the 6.4 MB xin gather working set. NT keeps ep out of
// L2 -> higher xin hit rate -> lower mean gather latency (the measured
// bottleneck: request-queue x latency). xin/x0h/xout stay normally cached.
__global__ __launch_bounds__(256) void spmm_kernel(
    const int* __restrict__ rp, const int2* __restrict__ ep,
    const half_t* __restrict__ xin, const half_t* __restrict__ x0h,
    half_t* __restrict__ xout, float* __restrict__ fout, int last)
{
  int gt = blockIdx.x * 256 + threadIdx.x;
  const int stride = SPMM_BLOCKS * 256;
  for (int u = gt; u < N_NODES * 8; u += stride) {
    int r = u >> 3;
    int c4 = (u & 7) * 4;
    int e0 = rp[r], e1 = rp[r + 1];

    float acc[4] = {0.f, 0.f, 0.f, 0.f};
    for (int e = e0; e < e1; e += 4) {
      i2v p0 = __builtin_nontemporal_load((const i2v*)(ep + e));
      i2v p1 = __builtin_nontemporal_load((const i2v*)(ep + e + 1));
      i2v p2 = __builtin_nontemporal_load((const i2v*)(ep + e + 2));
      i2v p3 = __builtin_nontemporal_load((const i2v*)(ep + e + 3));
      h4 g0 = *(const h4*)(xin + (size_t)p0[0] * D_OUT + c4);
      h4 g1 = *(const h4*)(xin + (size_t)p1[0] * D_OUT + c4);
      h4 g2 = *(const h4*)(xin + (size_t)p2[0] * D_OUT + c4);
      h4 g3 = *(const h4*)(xin + (size_t)p3[0] * D_OUT + c4);
      float v0 = __int_as_float(p0[1]);
      float v1 = __int_as_float(p1[1]);
      float v2 = __int_as_float(p2[1]);
      float v3 = __int_as_float(p3[1]);
#pragma unroll
      for (int j = 0; j < 4; ++j) {
        acc[j] = fmaf(v0, (float)g0[j], acc[j]);
        acc[j] = fmaf(v1, (float)g1[j], acc[j]);
        acc[j] = fmaf(v2, (float)g2[j], acc[j]);
        acc[j] = fmaf(v3, (float)g3[j], acc[j]);
      }
    }

    h4 x0v = *(const h4*)(x0h + (size_t)r * D_OUT + c4);
    if (last) {
      float4 o;
      o.x = 0.9f * acc[0] + 0.1f * (float)x0v[0];
      o.y = 0.9f * acc[1] + 0.1f * (float)x0v[1];
      o.z = 0.9f * acc[2] + 0.1f * (float)x0v[2];
      o.w = 0.9f * acc[3] + 0.1f * (float)x0v[3];
      *(float4*)(fout + (size_t)r * D_OUT + c4) = o;
    } else {
      h4 o;
#pragma unroll
      for (int j = 0; j < 4; ++j)
        o[j] = (half_t)(0.9f * acc[j] + 0.1f * (float)x0v[j]);
      *(h4*)(xout + (size_t)r * D_OUT + c4) = o;
    }
  }
}

extern "C" void kernel_launch(void* const* d_in, const int* in_sizes, int n_in,
                              void* d_out, int out_size, void* d_ws, size_t ws_size,
                              hipStream_t stream) {
  const float* F     = (const float*)d_in[0];
  const int*   row   = (const int*)  d_in[1];
  const int*   col   = (const int*)  d_in[2];
  const float* evals = (const float*)d_in[3];
  const float* W1    = (const float*)d_in[4];
  const float* b1    = (const float*)d_in[5];
  const float* W2    = (const float*)d_in[6];
  const float* b2    = (const float*)d_in[7];
  float* out = (float*)d_out;

  // workspace layout (~35.1 MB). ebuck aliases P+Q: ebuck is dead before the
  // first spmm writes P (stream-ordered).
  char* w = (char*)d_ws;
  half_t* x0h    = (half_t*)(w);                //  6,400,000
  half_t* P      = (half_t*)(w +  6400000);     //  6,400,000 (alias ebuck lo)
  half_t* Q      = (half_t*)(w + 12800000);     //  6,400,000 (alias ebuck hi)
  int2*   ebuck  = (int2*)  (w +  6400000);     // 12,800,000
  int2*   epack  = (int2*)  (w + 19200000);     // 15,400,000 (padded CSR)
  int*   row_ptr = (int*)   (w + 34600192);     //    400,128 (N+1)
  int*   bcnt    = (int*)   (w + 35000576);     //      1,024 (zeroed)
  int*   bfill   = (int*)   (w + 35001600);     //      1,024 (zeroed)
  int*   bbase   = (int*)   (w + 35002624);     //      1,024
  int*   pbase   = (int*)   (w + 35003648);     //      1,024
  half_t* W1T    = (half_t*)(w + 35004672);     //     32,768
  half_t* W2T    = (half_t*)(w + 35037440);     //      4,096

  // D0: bhist + weight pack (independent)
  hipMemsetAsync(bcnt, 0, 2048, stream);   // bcnt + bfill
  mix0_kernel<<<640 + 64, 256, 0, stream>>>(row, bcnt, W1, W2, W1T, W2T);

  // D1-D3: CSR chain, each overlapped with an MLP slice (mlp needs W1T: D0 done)
  mix1_kernel<<<1 + MLP_A, 256, 0, stream>>>(
      bcnt, bbase, pbase, F, W1T, b1, W2T, b2, x0h);
  mix2_kernel<<<NCHUNK + MLP_B, 256, 0, stream>>>(
      row, col, evals, bfill, bbase, ebuck, F, W1T, b1, W2T, b2, x0h);
  mix3_kernel<<<NBUCK + MLP_C, 256, 0, stream>>>(
      bbase, pbase, ebuck, epack, row_ptr, F, W1T, b1, W2T, b2, x0h);

  // 10 propagation rounds: x0h -> P -> Q -> ... final writes fp32 d_out
  for (int i = 0; i < NPROP; ++i) {
    const half_t* xin = (i == 0) ? x0h : ((i & 1) ? P : Q);
    half_t* xout = (i & 1) ? Q : P;
    int last = (i == NPROP - 1);
    spmm_kernel<<<SPMM_BLOCKS, 256, 0, stream>>>(
        row_ptr, epack, xin, x0h, xout, out, last);
  }
}

// Round 10
// 518.187 us; speedup vs baseline: 1.1528x; 1.1528x over previous
//
#include <hip/hip_runtime.h>

#define N_NODES 100000
#define N_EDGES 1600000
#define D_IN    256
#define D_HID   64
#define D_OUT   32
#define NPROP   10

#define NBUCK 196          // bucket = row >> 9 (512 rows/bucket)
#define CHUNK 6080         // edges per bscatter block (LDS-limited)
#define NCHUNK ((N_EDGES + CHUNK - 1) / CHUNK)   // 264

#define MLP_BLOCKS 1563    // ceil(6250 waves / 4)
#define MLP_A 700          // slice sizes: D1 / D2 / D3
#define MLP_B 500
#define MLP_C (MLP_BLOCKS - MLP_A - MLP_B)   // 363

#define SPMM_BLOCKS 2048   // exactly-resident grid; grid-stride over 800000 units

typedef _Float16 half_t;
typedef _Float16 h8  __attribute__((ext_vector_type(8)));
typedef _Float16 h4  __attribute__((ext_vector_type(4)));
typedef float    f4v __attribute__((ext_vector_type(4)));

// ==================== MLP body (round-6 code, as device fn) ====================
#define HSTRIDE 72
#define MLP_LDS_BYTES (4 * 16 * HSTRIDE * 2 + 4 * 16 * 32 * 2)   // 13312

static __device__ __forceinline__ void mlp_body(
    int mb, int t, char* smem,
    const float* __restrict__ F, const half_t* __restrict__ W1T,
    const float* __restrict__ b1, const half_t* __restrict__ W2T,
    const float* __restrict__ b2, half_t* __restrict__ x0h)
{
  half_t* h_lds   = (half_t*)smem;                       // 4*16*72
  half_t* out_lds = (half_t*)(smem + 4 * 16 * HSTRIDE * 2);  // 4*16*32
  int w = t >> 6, lane = t & 63;
  int m = lane & 15, q = lane >> 4;
  int gw = mb * 4 + w;
  int node0 = gw * 16;
  if (node0 > N_NODES - 16) node0 = N_NODES - 16;  // tail waves duplicate last tile

  const float* ap = F + (size_t)(node0 + m) * D_IN + q * 8;
  float4 fr[16];
#pragma unroll
  for (int s = 0; s < 8; ++s) {
    fr[2 * s]     = *(const float4*)(ap + s * 32);
    fr[2 * s + 1] = *(const float4*)(ap + s * 32 + 4);
  }

  h8 af[8];
#pragma unroll
  for (int s = 0; s < 8; ++s) {
    float4 f0 = fr[2 * s], f1 = fr[2 * s + 1];
    h8 a;
    a[0] = (_Float16)f0.x; a[1] = (_Float16)f0.y;
    a[2] = (_Float16)f0.z; a[3] = (_Float16)f0.w;
    a[4] = (_Float16)f1.x; a[5] = (_Float16)f1.y;
    a[6] = (_Float16)f1.z; a[7] = (_Float16)f1.w;
    af[s] = a;
  }

  f4v acc[4];
#pragma unroll
  for (int i = 0; i < 4; ++i) acc[i] = (f4v){0.f, 0.f, 0.f, 0.f};
  const half_t* bp = W1T + (size_t)m * D_IN + q * 8;
#pragma unroll
  for (int s = 0; s < 8; ++s) {
    h8 b0 = *(const h8*)(bp + 0 * 16 * D_IN + s * 32);
    h8 b1v = *(const h8*)(bp + 1 * 16 * D_IN + s * 32);
    h8 b2v = *(const h8*)(bp + 2 * 16 * D_IN + s * 32);
    h8 b3v = *(const h8*)(bp + 3 * 16 * D_IN + s * 32);
    acc[0] = __builtin_amdgcn_mfma_f32_16x16x32_f16(af[s], b0, acc[0], 0, 0, 0);
    acc[1] = __builtin_amdgcn_mfma_f32_16x16x32_f16(af[s], b1v, acc[1], 0, 0, 0);
    acc[2] = __builtin_amdgcn_mfma_f32_16x16x32_f16(af[s], b2v, acc[2], 0, 0, 0);
    acc[3] = __builtin_amdgcn_mfma_f32_16x16x32_f16(af[s], b3v, acc[3], 0, 0, 0);
  }

  half_t* hw = h_lds + w * 16 * HSTRIDE;
#pragma unroll
  for (int ht = 0; ht < 4; ++ht) {
    float bb = b1[ht * 16 + m];
#pragma unroll
    for (int i = 0; i < 4; ++i) {
      float hv = fmaxf(acc[ht][i] + bb, 0.f);
      hw[(q * 4 + i) * HSTRIDE + ht * 16 + m] = (half_t)hv;
    }
  }
  __syncthreads();

  f4v o0 = {0.f, 0.f, 0.f, 0.f}, o1 = {0.f, 0.f, 0.f, 0.f};
#pragma unroll
  for (int s = 0; s < 2; ++s) {
    h8 a = *(const h8*)(hw + m * HSTRIDE + s * 32 + q * 8);
    h8 bb0 = *(const h8*)(W2T + (size_t)m * D_HID + s * 32 + q * 8);
    h8 bb1 = *(const h8*)(W2T + (size_t)(16 + m) * D_HID + s * 32 + q * 8);
    o0 = __builtin_amdgcn_mfma_f32_16x16x32_f16(a, bb0, o0, 0, 0, 0);
    o1 = __builtin_amdgcn_mfma_f32_16x16x32_f16(a, bb1, o1, 0, 0, 0);
  }
  half_t* ow = out_lds + w * 16 * 32;
  {
    float c0 = b2[m], c1 = b2[16 + m];
#pragma unroll
    for (int i = 0; i < 4; ++i) {
      ow[(q * 4 + i) * 32 + m]      = (half_t)(o0[i] + c0);
      ow[(q * 4 + i) * 32 + 16 + m] = (half_t)(o1[i] + c1);
    }
  }
  __syncthreads();

  {
    int nl = lane >> 2, qq = lane & 3;
    *(int4*)(x0h + (size_t)(node0 + nl) * D_OUT + qq * 8) =
        *(const int4*)(ow + nl * 32 + qq * 8);
  }
}

// ==================== D0: bhist (b<640) + weight pack (b>=640) ====================
__global__ __launch_bounds__(256) void mix0_kernel(
    const int* __restrict__ row, int* __restrict__ bcnt,
    const float* __restrict__ W1, const float* __restrict__ W2,
    half_t* __restrict__ W1T, half_t* __restrict__ W2T)
{
  __shared__ int lb[NBUCK];
  int b = blockIdx.x, t = threadIdx.x;
  if (b < 640) {
    for (int i = t; i < NBUCK; i += 256) lb[i] = 0;
    __syncthreads();
    const int stride = 640 * 256;
    for (int e = b * 256 + t; e < N_EDGES; e += stride)
      atomicAdd(&lb[row[e] >> 9], 1);
    __syncthreads();
    for (int i = t; i < NBUCK; i += 256)
      if (lb[i]) atomicAdd(&bcnt[i], lb[i]);
  } else {
    int g = (b - 640) * 256 + t;
    if (g < 64 * 256) { int n = g >> 8, k = g & 255; W1T[g] = (half_t)W1[k * 64 + n]; }
    if (g < 32 * 64)  { int n = g >> 6, k = g & 63;  W2T[g] = (half_t)W2[k * 32 + n]; }
  }
}

// ==================== D1: bscan (b==0) + mlp slice A ====================
__global__ __launch_bounds__(256, 2) void mix1_kernel(
    const int* __restrict__ bcnt, int* __restrict__ bbase, int* __restrict__ pbase,
    const float* __restrict__ F, const half_t* __restrict__ W1T,
    const float* __restrict__ b1, const half_t* __restrict__ W2T,
    const float* __restrict__ b2, half_t* __restrict__ x0h)
{
  __shared__ __align__(16) char smem[MLP_LDS_BYTES];   // mlp needs 13312; bscan 2KB
  int b = blockIdx.x, t = threadIdx.x;
  if (b == 0) {
    int* l1 = (int*)smem;           // 256 ints
    int* l2 = (int*)smem + 256;     // 256 ints
    int a = (t < NBUCK) ? bcnt[t] : 0;
    int r = (t < NBUCK) ? (((a + 3) & ~3) + 3 * 512) : 0;
    l1[t] = a; l2[t] = r;
    __syncthreads();
    for (int off = 1; off < 256; off <<= 1) {
      int x1 = (t >= off) ? l1[t - off] : 0;
      int x2 = (t >= off) ? l2[t - off] : 0;
      __syncthreads();
      l1[t] += x1; l2[t] += x2;
      __syncthreads();
    }
    if (t < NBUCK) { bbase[t] = l1[t] - a; pbase[t] = l2[t] - r; }
    if (t == NBUCK - 1) { bbase[NBUCK] = l1[t]; pbase[NBUCK] = l2[t]; }
  } else {
    mlp_body(b - 1, t, smem, F, W1T, b1, W2T, b2, x0h);
  }
}

// ==================== D2: bscatter (b<264) + mlp slice B ====================
__global__ __launch_bounds__(256, 2) void mix2_kernel(
    const int* __restrict__ row, const int* __restrict__ col,
    const float* __restrict__ vals, int* __restrict__ bfill,
    const int* __restrict__ bbase, int2* __restrict__ ebuck,
    const float* __restrict__ F, const half_t* __restrict__ W1T,
    const float* __restrict__ b1, const half_t* __restrict__ W2T,
    const float* __restrict__ b2, half_t* __restrict__ x0h)
{
  __shared__ int2 img[CHUNK];
  __shared__ unsigned short sbk[CHUNK];
  __shared__ int cnt[NBUCK], base[NBUCK], gb[NBUCK], fil[NBUCK];
  __shared__ int ssc[256];
  __shared__ __align__(16) char smem[MLP_LDS_BYTES];
  int b = blockIdx.x, t = threadIdx.x;

  if (b < NCHUNK) {
    int e0 = b * CHUNK;
    int n = min(CHUNK, N_EDGES - e0);

    for (int i = t; i < NBUCK; i += 256) { cnt[i] = 0; fil[i] = 0; }
    __syncthreads();
    for (int i = t; i < n; i += 256) atomicAdd(&cnt[row[e0 + i] >> 9], 1);
    __syncthreads();
    int c = (t < NBUCK) ? cnt[t] : 0;
    ssc[t] = c;
    __syncthreads();
    for (int off = 1; off < 256; off <<= 1) {
      int add = (t >= off) ? ssc[t - off] : 0;
      __syncthreads();
      ssc[t] += add;
      __syncthreads();
    }
    if (t < NBUCK) {
      base[t] = ssc[t] - c;
      gb[t] = c ? atomicAdd(&bfill[t], c) : 0;
    }
    __syncthreads();
    for (int i = t; i < n; i += 256) {
      int r = row[e0 + i];
      int bk = r >> 9;
      int p = base[bk] + atomicAdd(&fil[bk], 1);
      img[p] = make_int2(col[e0 + i] | ((r & 511) << 17),
                         __float_as_int(vals[e0 + i]));
      sbk[p] = (unsigned short)bk;
    }
    __syncthreads();
    for (int i = t; i < n; i += 256) {
      int bk = sbk[i];
      ebuck[bbase[bk] + gb[bk] + (i - base[bk])] = img[i];
    }
  } else {
    mlp_body(MLP_A + (b - NCHUNK), t, smem, F, W1T, b1, W2T, b2, x0h);
  }
}

// ==================== D3: bsort (b<196) + mlp slice C ====================
__global__ __launch_bounds__(256, 2) void mix3_kernel(
    const int* __restrict__ bbase, const int* __restrict__ pbase,
    const int2* __restrict__ ebuck, int2* __restrict__ epack,
    int* __restrict__ row_ptr,
    const float* __restrict__ F, const half_t* __restrict__ W1T,
    const float* __restrict__ b1, const half_t* __restrict__ W2T,
    const float* __restrict__ b2, half_t* __restrict__ x0h)
{
  __shared__ int acnt[512], loff[513], lfill[512], ssc[256];
  __shared__ __align__(16) char smem[MLP_LDS_BYTES];
  int b = blockIdx.x, t = threadIdx.x;

  if (b < NBUCK) {
    int r0 = b * 512;
    int nr = min(512, N_NODES - r0);
    int eb = bbase[b];
    int ne = bbase[b + 1] - eb;
    int pb = pbase[b];

    acnt[t] = 0; acnt[t + 256] = 0;
    lfill[t] = 0; lfill[t + 256] = 0;
    __syncthreads();
    for (int i = t; i < ne; i += 256)
      atomicAdd(&acnt[((unsigned)ebuck[eb + i].x) >> 17], 1);
    __syncthreads();
    int i0 = 2 * t, i1 = 2 * t + 1;
    int a0 = acnt[i0], a1 = acnt[i1];
    int p0 = (a0 + 3) & ~3, p1 = (a1 + 3) & ~3;
    int s = p0 + p1;
    ssc[t] = s;
    __syncthreads();
    for (int off = 1; off < 256; off <<= 1) {
      int add = (t >= off) ? ssc[t - off] : 0;
      __syncthreads();
      ssc[t] += add;
      __syncthreads();
    }
    int ex = ssc[t] - s;
    loff[i0] = ex;
    loff[i1] = ex + p0;
    if (t == 255) loff[512] = ssc[255];
    __syncthreads();
    int T = ssc[255];
    int slack = (pbase[b + 1] - pb) - T;
    int units = min(slack >> 2, nr);
    if (i0 < nr) row_ptr[r0 + i0] = pb + loff[i0] + 4 * min(i0, units);
    if (i1 < nr) row_ptr[r0 + i1] = pb + loff[i1] + 4 * min(i1, units);
    if (b == NBUCK - 1 && t == 0)
      row_ptr[N_NODES] = pb + loff[nr] + 4 * units;
    __syncthreads();
    for (int i = t; i < ne; i += 256) {
      int2 ed = ebuck[eb + i];
      int lr = ((unsigned)ed.x) >> 17;
      int cl = ed.x & 0x1FFFF;
      int p = loff[lr] + 4 * min(lr, units) + atomicAdd(&lfill[lr], 1);
      epack[pb + p] = make_int2(cl, ed.y);
    }
    __syncthreads();
    for (int i = t; i < nr; i += 256) {
      int a = acnt[i];
      int size_i = ((a + 3) & ~3) + 4 * (i < units);
      int st = loff[i] + 4 * min(i, units);
      for (int p = st + a; p < st + size_i; ++p)
        epack[pb + p] = make_int2(0, 0);
    }
  } else {
    mlp_body(MLP_A + MLP_B + (b - NBUCK), t, smem, F, W1T, b1, W2T, b2, x0h);
  }
}

// ==================== propagation (round-8 + 1-trip software pipeline) =====
// Per-trip serial chain was: ep load (wait) -> gather (wait) -> FMA.
// Pipeline: prologue issues trip-0 ep+gathers; each iteration issues trip
// t+1's ep quad and gathers BEFORE consuming trip t's gathers in the FMAs,
// so the FMA waitcnt targets loads issued a full trip earlier. Per-trip
// serial cost drops from ~(ep+gather) latency to ~ep latency. All loads
// normally cached (NT was measured -76 us in round 9). FMA order unchanged
// -> bitwise-identical output. Last-trip prefetch clamps to the current
// trip (valid addresses, dead values).
__global__ __launch_bounds__(256) void spmm_kernel(
    const int* __restrict__ rp, const int2* __restrict__ ep,
    const half_t* __restrict__ xin, const half_t* __restrict__ x0h,
    half_t* __restrict__ xout, float* __restrict__ fout, int last)
{
  int gt = blockIdx.x * 256 + threadIdx.x;
  const int stride = SPMM_BLOCKS * 256;
  for (int u = gt; u < N_NODES * 8; u += stride) {
    int r = u >> 3;
    int c4 = (u & 7) * 4;
    int e0 = rp[r], e1 = rp[r + 1];

    float acc[4] = {0.f, 0.f, 0.f, 0.f};
    if (e0 < e1) {
      int4 qa = *(const int4*)(ep + e0);
      int4 qb = *(const int4*)(ep + e0 + 2);
      h4 g0 = *(const h4*)(xin + (size_t)qa.x * D_OUT + c4);
      h4 g1 = *(const h4*)(xin + (size_t)qa.z * D_OUT + c4);
      h4 g2 = *(const h4*)(xin + (size_t)qb.x * D_OUT + c4);
      h4 g3 = *(const h4*)(xin + (size_t)qb.z * D_OUT + c4);
      for (int e = e0; e < e1; e += 4) {
        int ef = (e + 4 < e1) ? (e + 4) : e;   // clamp on last trip
        int4 qa2 = *(const int4*)(ep + ef);
        int4 qb2 = *(const int4*)(ep + ef + 2);
        h4 n0 = *(const h4*)(xin + (size_t)qa2.x * D_OUT + c4);
        h4 n1 = *(const h4*)(xin + (size_t)qa2.z * D_OUT + c4);
        h4 n2 = *(const h4*)(xin + (size_t)qb2.x * D_OUT + c4);
        h4 n3 = *(const h4*)(xin + (size_t)qb2.z * D_OUT + c4);
        float v0 = __int_as_float(qa.y);
        float v1 = __int_as_float(qa.w);
        float v2 = __int_as_float(qb.y);
        float v3 = __int_as_float(qb.w);
#pragma unroll
        for (int j = 0; j < 4; ++j) {
          acc[j] = fmaf(v0, (float)g0[j], acc[j]);
          acc[j] = fmaf(v1, (float)g1[j], acc[j]);
          acc[j] = fmaf(v2, (float)g2[j], acc[j]);
          acc[j] = fmaf(v3, (float)g3[j], acc[j]);
        }
        qa = qa2; qb = qb2;
        g0 = n0; g1 = n1; g2 = n2; g3 = n3;
      }
    }

    h4 x0v = *(const h4*)(x0h + (size_t)r * D_OUT + c4);
    if (last) {
      float4 o;
      o.x = 0.9f * acc[0] + 0.1f * (float)x0v[0];
      o.y = 0.9f * acc[1] + 0.1f * (float)x0v[1];
      o.z = 0.9f * acc[2] + 0.1f * (float)x0v[2];
      o.w = 0.9f * acc[3] + 0.1f * (float)x0v[3];
      *(float4*)(fout + (size_t)r * D_OUT + c4) = o;
    } else {
      h4 o;
#pragma unroll
      for (int j = 0; j < 4; ++j)
        o[j] = (half_t)(0.9f * acc[j] + 0.1f * (float)x0v[j]);
      *(h4*)(xout + (size_t)r * D_OUT + c4) = o;
    }
  }
}

extern "C" void kernel_launch(void* const* d_in, const int* in_sizes, int n_in,
                              void* d_out, int out_size, void* d_ws, size_t ws_size,
                              hipStream_t stream) {
  const float* F     = (const float*)d_in[0];
  const int*   row   = (const int*)  d_in[1];
  const int*   col   = (const int*)  d_in[2];
  const float* evals = (const float*)d_in[3];
  const float* W1    = (const float*)d_in[4];
  const float* b1    = (const float*)d_in[5];
  const float* W2    = (const float*)d_in[6];
  const float* b2    = (const float*)d_in[7];
  float* out = (float*)d_out;

  // workspace layout (~35.1 MB). ebuck aliases P+Q: ebuck is dead before the
  // first spmm writes P (stream-ordered).
  char* w = (char*)d_ws;
  half_t* x0h    = (half_t*)(w);                //  6,400,000
  half_t* P      = (half_t*)(w +  6400000);     //  6,400,000 (alias ebuck lo)
  half_t* Q      = (half_t*)(w + 12800000);     //  6,400,000 (alias ebuck hi)
  int2*   ebuck  = (int2*)  (w +  6400000);     // 12,800,000
  int2*   epack  = (int2*)  (w + 19200000);     // 15,400,000 (padded CSR)
  int*   row_ptr = (int*)   (w + 34600192);     //    400,128 (N+1)
  int*   bcnt    = (int*)   (w + 35000576);     //      1,024 (zeroed)
  int*   bfill   = (int*)   (w + 35001600);     //      1,024 (zeroed)
  int*   bbase   = (int*)   (w + 35002624);     //      1,024
  int*   pbase   = (int*)   (w + 35003648);     //      1,024
  half_t* W1T    = (half_t*)(w + 35004672);     //     32,768
  half_t* W2T    = (half_t*)(w + 35037440);     //      4,096

  // D0: bhist + weight pack (independent)
  hipMemsetAsync(bcnt, 0, 2048, stream);   // bcnt + bfill
  mix0_kernel<<<640 + 64, 256, 0, stream>>>(row, bcnt, W1, W2, W1T, W2T);

  // D1-D3: CSR chain, each overlapped with an MLP slice (mlp needs W1T: D0 done)
  mix1_kernel<<<1 + MLP_A, 256, 0, stream>>>(
      bcnt, bbase, pbase, F, W1T, b1, W2T, b2, x0h);
  mix2_kernel<<<NCHUNK + MLP_B, 256, 0, stream>>>(
      row, col, evals, bfill, bbase, ebuck, F, W1T, b1, W2T, b2, x0h);
  mix3_kernel<<<NBUCK + MLP_C, 256, 0, stream>>>(
      bbase, pbase, ebuck, epack, row_ptr, F, W1T, b1, W2T, b2, x0h);

  // 10 propagation rounds: x0h -> P -> Q -> ... final writes fp32 d_out
  for (int i = 0; i < NPROP; ++i) {
    const half_t* xin = (i == 0) ? x0h : ((i & 1) ? P : Q);
    half_t* xout = (i & 1) ? Q : P;
    int last = (i == NPROP - 1);
    spmm_kernel<<<SPMM_BLOCKS, 256, 0, stream>>>(
        row_ptr, epack, xin, x0h, xout, out, last);
  }
}

// Round 12
// 517.564 us; speedup vs baseline: 1.1542x; 1.0012x over previous
//
#include <hip/hip_runtime.h>

#define N_NODES 100000
#define N_EDGES 1600000
#define D_IN    256
#define D_HID   64
#define D_OUT   32
#define NPROP   10

#define NBUCK 196          // bucket = row >> 9 (512 rows/bucket)
#define CHUNK 6080         // edges per bscatter block (LDS-limited)
#define NCHUNK ((N_EDGES + CHUNK - 1) / CHUNK)   // 264

#define MLP_BLOCKS 1563    // ceil(6250 waves / 4)
#define MLP_A 700          // slice sizes: D1 / D2 / D3
#define MLP_B 500
#define MLP_C (MLP_BLOCKS - MLP_A - MLP_B)   // 363

#define SPMM_BLOCKS 2048   // exactly-resident grid; grid-stride over 800000 units

#define CC 8               // col-chunks per row (order-only: layout unchanged)
#define CDIV 12500         // chunk = col / CDIV  (0..7 for col < 100000)

typedef _Float16 half_t;
typedef _Float16 h8  __attribute__((ext_vector_type(8)));
typedef _Float16 h4  __attribute__((ext_vector_type(4)));
typedef float    f4v __attribute__((ext_vector_type(4)));

// ==================== MLP body (round-6 code, as device fn) ====================
#define HSTRIDE 72
#define MLP_LDS_BYTES (4 * 16 * HSTRIDE * 2 + 4 * 16 * 32 * 2)   // 13312

static __device__ __forceinline__ void mlp_body(
    int mb, int t, char* smem,
    const float* __restrict__ F, const half_t* __restrict__ W1T,
    const float* __restrict__ b1, const half_t* __restrict__ W2T,
    const float* __restrict__ b2, half_t* __restrict__ x0h)
{
  half_t* h_lds   = (half_t*)smem;                       // 4*16*72
  half_t* out_lds = (half_t*)(smem + 4 * 16 * HSTRIDE * 2);  // 4*16*32
  int w = t >> 6, lane = t & 63;
  int m = lane & 15, q = lane >> 4;
  int gw = mb * 4 + w;
  int node0 = gw * 16;
  if (node0 > N_NODES - 16) node0 = N_NODES - 16;  // tail waves duplicate last tile

  const float* ap = F + (size_t)(node0 + m) * D_IN + q * 8;
  float4 fr[16];
#pragma unroll
  for (int s = 0; s < 8; ++s) {
    fr[2 * s]     = *(const float4*)(ap + s * 32);
    fr[2 * s + 1] = *(const float4*)(ap + s * 32 + 4);
  }

  h8 af[8];
#pragma unroll
  for (int s = 0; s < 8; ++s) {
    float4 f0 = fr[2 * s], f1 = fr[2 * s + 1];
    h8 a;
    a[0] = (_Float16)f0.x; a[1] = (_Float16)f0.y;
    a[2] = (_Float16)f0.z; a[3] = (_Float16)f0.w;
    a[4] = (_Float16)f1.x; a[5] = (_Float16)f1.y;
    a[6] = (_Float16)f1.z; a[7] = (_Float16)f1.w;
    af[s] = a;
  }

  f4v acc[4];
#pragma unroll
  for (int i = 0; i < 4; ++i) acc[i] = (f4v){0.f, 0.f, 0.f, 0.f};
  const half_t* bp = W1T + (size_t)m * D_IN + q * 8;
#pragma unroll
  for (int s = 0; s < 8; ++s) {
    h8 b0 = *(const h8*)(bp + 0 * 16 * D_IN + s * 32);
    h8 b1v = *(const h8*)(bp + 1 * 16 * D_IN + s * 32);
    h8 b2v = *(const h8*)(bp + 2 * 16 * D_IN + s * 32);
    h8 b3v = *(const h8*)(bp + 3 * 16 * D_IN + s * 32);
    acc[0] = __builtin_amdgcn_mfma_f32_16x16x32_f16(af[s], b0, acc[0], 0, 0, 0);
    acc[1] = __builtin_amdgcn_mfma_f32_16x16x32_f16(af[s], b1v, acc[1], 0, 0, 0);
    acc[2] = __builtin_amdgcn_mfma_f32_16x16x32_f16(af[s], b2v, acc[2], 0, 0, 0);
    acc[3] = __builtin_amdgcn_mfma_f32_16x16x32_f16(af[s], b3v, acc[3], 0, 0, 0);
  }

  half_t* hw = h_lds + w * 16 * HSTRIDE;
#pragma unroll
  for (int ht = 0; ht < 4; ++ht) {
    float bb = b1[ht * 16 + m];
#pragma unroll
    for (int i = 0; i < 4; ++i) {
      float hv = fmaxf(acc[ht][i] + bb, 0.f);
      hw[(q * 4 + i) * HSTRIDE + ht * 16 + m] = (half_t)hv;
    }
  }
  __syncthreads();

  f4v o0 = {0.f, 0.f, 0.f, 0.f}, o1 = {0.f, 0.f, 0.f, 0.f};
#pragma unroll
  for (int s = 0; s < 2; ++s) {
    h8 a = *(const h8*)(hw + m * HSTRIDE + s * 32 + q * 8);
    h8 bb0 = *(const h8*)(W2T + (size_t)m * D_HID + s * 32 + q * 8);
    h8 bb1 = *(const h8*)(W2T + (size_t)(16 + m) * D_HID + s * 32 + q * 8);
    o0 = __builtin_amdgcn_mfma_f32_16x16x32_f16(a, bb0, o0, 0, 0, 0);
    o1 = __builtin_amdgcn_mfma_f32_16x16x32_f16(a, bb1, o1, 0, 0, 0);
  }
  half_t* ow = out_lds + w * 16 * 32;
  {
    float c0 = b2[m], c1 = b2[16 + m];
#pragma unroll
    for (int i = 0; i < 4; ++i) {
      ow[(q * 4 + i) * 32 + m]      = (half_t)(o0[i] + c0);
      ow[(q * 4 + i) * 32 + 16 + m] = (half_t)(o1[i] + c1);
    }
  }
  __syncthreads();

  {
    int nl = lane >> 2, qq = lane & 3;
    *(int4*)(x0h + (size_t)(node0 + nl) * D_OUT + qq * 8) =
        *(const int4*)(ow + nl * 32 + qq * 8);
  }
}

// ==================== D0: bhist (b<640) + weight pack (b>=640) ====================
__global__ __launch_bounds__(256) void mix0_kernel(
    const int* __restrict__ row, int* __restrict__ bcnt,
    const float* __restrict__ W1, const float* __restrict__ W2,
    half_t* __restrict__ W1T, half_t* __restrict__ W2T)
{
  __shared__ int lb[NBUCK];
  int b = blockIdx.x, t = threadIdx.x;
  if (b < 640) {
    for (int i = t; i < NBUCK; i += 256) lb[i] = 0;
    __syncthreads();
    const int stride = 640 * 256;
    for (int e = b * 256 + t; e < N_EDGES; e += stride)
      atomicAdd(&lb[row[e] >> 9], 1);
    __syncthreads();
    for (int i = t; i < NBUCK; i += 256)
      if (lb[i]) atomicAdd(&bcnt[i], lb[i]);
  } else {
    int g = (b - 640) * 256 + t;
    if (g < 64 * 256) { int n = g >> 8, k = g & 255; W1T[g] = (half_t)W1[k * 64 + n]; }
    if (g < 32 * 64)  { int n = g >> 6, k = g & 63;  W2T[g] = (half_t)W2[k * 32 + n]; }
  }
}

// ==================== D1: bscan (b==0) + mlp slice A ====================
__global__ __launch_bounds__(256, 2) void mix1_kernel(
    const int* __restrict__ bcnt, int* __restrict__ bbase, int* __restrict__ pbase,
    const float* __restrict__ F, const half_t* __restrict__ W1T,
    const float* __restrict__ b1, const half_t* __restrict__ W2T,
    const float* __restrict__ b2, half_t* __restrict__ x0h)
{
  __shared__ __align__(16) char smem[MLP_LDS_BYTES];   // mlp needs 13312; bscan 2KB
  int b = blockIdx.x, t = threadIdx.x;
  if (b == 0) {
    int* l1 = (int*)smem;           // 256 ints
    int* l2 = (int*)smem + 256;     // 256 ints
    int a = (t < NBUCK) ? bcnt[t] : 0;
    int r = (t < NBUCK) ? (((a + 3) & ~3) + 3 * 512) : 0;
    l1[t] = a; l2[t] = r;
    __syncthreads();
    for (int off = 1; off < 256; off <<= 1) {
      int x1 = (t >= off) ? l1[t - off] : 0;
      int x2 = (t >= off) ? l2[t - off] : 0;
      __syncthreads();
      l1[t] += x1; l2[t] += x2;
      __syncthreads();
    }
    if (t < NBUCK) { bbase[t] = l1[t] - a; pbase[t] = l2[t] - r; }
    if (t == NBUCK - 1) { bbase[NBUCK] = l1[t]; pbase[NBUCK] = l2[t]; }
  } else {
    mlp_body(b - 1, t, smem, F, W1T, b1, W2T, b2, x0h);
  }
}

// ==================== D2: bscatter (b<264) + mlp slice B ====================
__global__ __launch_bounds__(256, 2) void mix2_kernel(
    const int* __restrict__ row, const int* __restrict__ col,
    const float* __restrict__ vals, int* __restrict__ bfill,
    const int* __restrict__ bbase, int2* __restrict__ ebuck,
    const float* __restrict__ F, const half_t* __restrict__ W1T,
    const float* __restrict__ b1, const half_t* __restrict__ W2T,
    const float* __restrict__ b2, half_t* __restrict__ x0h)
{
  __shared__ int2 img[CHUNK];
  __shared__ unsigned short sbk[CHUNK];
  __shared__ int cnt[NBUCK], base[NBUCK], gb[NBUCK], fil[NBUCK];
  __shared__ int ssc[256];
  __shared__ __align__(16) char smem[MLP_LDS_BYTES];
  int b = blockIdx.x, t = threadIdx.x;

  if (b < NCHUNK) {
    int e0 = b * CHUNK;
    int n = min(CHUNK, N_EDGES - e0);

    for (int i = t; i < NBUCK; i += 256) { cnt[i] = 0; fil[i] = 0; }
    __syncthreads();
    for (int i = t; i < n; i += 256) atomicAdd(&cnt[row[e0 + i] >> 9], 1);
    __syncthreads();
    int c = (t < NBUCK) ? cnt[t] : 0;
    ssc[t] = c;
    __syncthreads();
    for (int off = 1; off < 256; off <<= 1) {
      int add = (t >= off) ? ssc[t - off] : 0;
      __syncthreads();
      ssc[t] += add;
      __syncthreads();
    }
    if (t < NBUCK) {
      base[t] = ssc[t] - c;
      gb[t] = c ? atomicAdd(&bfill[t], c) : 0;
    }
    __syncthreads();
    for (int i = t; i < n; i += 256) {
      int r = row[e0 + i];
      int bk = r >> 9;
      int p = base[bk] + atomicAdd(&fil[bk], 1);
      img[p] = make_int2(col[e0 + i] | ((r & 511) << 17),
                         __float_as_int(vals[e0 + i]));
      sbk[p] = (unsigned short)bk;
    }
    __syncthreads();
    for (int i = t; i < n; i += 256) {
      int bk = sbk[i];
      ebuck[bbase[bk] + gb[bk] + (i - base[bk])] = img[i];
    }
  } else {
    mlp_body(MLP_A + (b - NCHUNK), t, smem, F, W1T, b1, W2T, b2, x0h);
  }
}

// ==================== D3: bsort (b<196, col-chunk order) + mlp slice C =====
// Edges within each row are grouped by col-chunk (CC=8 ranges of 12500
// source rows). ORDER-ONLY change: row padding, row_ptr, epack layout are
// bitwise-identical to round 8/10. All waves start their rows at chunk 0
// -> the chip's instantaneous gather working set drops from 6.4 MB (random)
// to ~0.8-2 MB (phase-correlated) -> fits XCD L2 -> lower mean gather
// latency (the measured bottleneck). Per-row summation order was already
// atomic-race nondeterministic; absmax stable at 1 ulp across orderings.
__global__ __launch_bounds__(256, 2) void mix3_kernel(
    const int* __restrict__ bbase, const int* __restrict__ pbase,
    const int2* __restrict__ ebuck, int2* __restrict__ epack,
    int* __restrict__ row_ptr,
    const float* __restrict__ F, const half_t* __restrict__ W1T,
    const float* __restrict__ b1, const half_t* __restrict__ W2T,
    const float* __restrict__ b2, half_t* __restrict__ x0h)
{
  __shared__ int acnt2[512 * CC];   // per (row,chunk) count -> exclusive offset
  __shared__ int cfil[512 * CC];
  __shared__ int rowa[512], loff[513], ssc[256];
  __shared__ __align__(16) char smem[MLP_LDS_BYTES];
  int b = blockIdx.x, t = threadIdx.x;

  if (b < NBUCK) {
    int r0 = b * 512;
    int nr = min(512, N_NODES - r0);
    int eb = bbase[b];
    int ne = bbase[b + 1] - eb;
    int pb = pbase[b];

    for (int i = t; i < 512 * CC; i += 256) { acnt2[i] = 0; cfil[i] = 0; }
    __syncthreads();
    // phase A: (row, col-chunk) histogram
    for (int i = t; i < ne; i += 256) {
      int ex = ebuck[eb + i].x;
      int lr = ((unsigned)ex) >> 17;
      int cl = ex & 0x1FFFF;
      atomicAdd(&acnt2[lr * CC + cl / CDIV], 1);
    }
    __syncthreads();
    // phase B: in-place per-row chunk prefix (each thread owns 2 rows) +
    // padded row scan (identical layout math to round 8)
    int i0 = 2 * t, i1 = 2 * t + 1;
    int a0 = 0, a1 = 0;
#pragma unroll
    for (int cc = 0; cc < CC; ++cc) {
      int c = acnt2[i0 * CC + cc]; acnt2[i0 * CC + cc] = a0; a0 += c;
    }
#pragma unroll
    for (int cc = 0; cc < CC; ++cc) {
      int c = acnt2[i1 * CC + cc]; acnt2[i1 * CC + cc] = a1; a1 += c;
    }
    rowa[i0] = a0; rowa[i1] = a1;
    int p0 = (a0 + 3) & ~3, p1 = (a1 + 3) & ~3;
    int s = p0 + p1;
    ssc[t] = s;
    __syncthreads();
    for (int off = 1; off < 256; off <<= 1) {
      int add = (t >= off) ? ssc[t - off] : 0;
      __syncthreads();
      ssc[t] += add;
      __syncthreads();
    }
    int ex2 = ssc[t] - s;
    loff[i0] = ex2;
    loff[i1] = ex2 + p0;
    if (t == 255) loff[512] = ssc[255];
    __syncthreads();
    int T = ssc[255];
    int slack = (pbase[b + 1] - pb) - T;
    int units = min(slack >> 2, nr);
    if (i0 < nr) row_ptr[r0 + i0] = pb + loff[i0] + 4 * min(i0, units);
    if (i1 < nr) row_ptr[r0 + i1] = pb + loff[i1] + 4 * min(i1, units);
    if (b == NBUCK - 1 && t == 0)
      row_ptr[N_NODES] = pb + loff[nr] + 4 * units;
    __syncthreads();
    // phase C: scatter, placed by (row, col-chunk) slot
    for (int i = t; i < ne; i += 256) {
      int2 ed = ebuck[eb + i];
      int lr = ((unsigned)ed.x) >> 17;
      int cl = ed.x & 0x1FFFF;
      int cc = cl / CDIV;
      int p = loff[lr] + 4 * min(lr, units) + acnt2[lr * CC + cc]
            + atomicAdd(&cfil[lr * CC + cc], 1);
      epack[pb + p] = make_int2(cl, ed.y);
    }
    __syncthreads();
    // phase D: zero-weight pad edges (row totals in rowa)
    for (int i = t; i < nr; i += 256) {
      int a = rowa[i];
      int size_i = ((a + 3) & ~3) + 4 * (i < units);
      int st = loff[i] + 4 * min(i, units);
      for (int p = st + a; p < st + size_i; ++p)
        epack[pb + p] = make_int2(0, 0);
    }
  } else {
    mlp_body(MLP_A + MLP_B + (b - NBUCK), t, smem, F, W1T, b1, W2T, b2, x0h);
  }
}

// ==================== propagation (round-10: 1-trip software pipeline) =====
__global__ __launch_bounds__(256) void spmm_kernel(
    const int* __restrict__ rp, const int2* __restrict__ ep,
    const half_t* __restrict__ xin, const half_t* __restrict__ x0h,
    half_t* __restrict__ xout, float* __restrict__ fout, int last)
{
  int gt = blockIdx.x * 256 + threadIdx.x;
  const int stride = SPMM_BLOCKS * 256;
  for (int u = gt; u < N_NODES * 8; u += stride) {
    int r = u >> 3;
    int c4 = (u & 7) * 4;
    int e0 = rp[r], e1 = rp[r + 1];

    float acc[4] = {0.f, 0.f, 0.f, 0.f};
    if (e0 < e1) {
      int4 qa = *(const int4*)(ep + e0);
      int4 qb = *(const int4*)(ep + e0 + 2);
      h4 g0 = *(const h4*)(xin + (size_t)qa.x * D_OUT + c4);
      h4 g1 = *(const h4*)(xin + (size_t)qa.z * D_OUT + c4);
      h4 g2 = *(const h4*)(xin + (size_t)qb.x * D_OUT + c4);
      h4 g3 = *(const h4*)(xin + (size_t)qb.z * D_OUT + c4);
      for (int e = e0; e < e1; e += 4) {
        int ef = (e + 4 < e1) ? (e + 4) : e;   // clamp on last trip
        int4 qa2 = *(const int4*)(ep + ef);
        int4 qb2 = *(const int4*)(ep + ef + 2);
        h4 n0 = *(const h4*)(xin + (size_t)qa2.x * D_OUT + c4);
        h4 n1 = *(const h4*)(xin + (size_t)qa2.z * D_OUT + c4);
        h4 n2 = *(const h4*)(xin + (size_t)qb2.x * D_OUT + c4);
        h4 n3 = *(const h4*)(xin + (size_t)qb2.z * D_OUT + c4);
        float v0 = __int_as_float(qa.y);
        float v1 = __int_as_float(qa.w);
        float v2 = __int_as_float(qb.y);
        float v3 = __int_as_float(qb.w);
#pragma unroll
        for (int j = 0; j < 4; ++j) {
          acc[j] = fmaf(v0, (float)g0[j], acc[j]);
          acc[j] = fmaf(v1, (float)g1[j], acc[j]);
          acc[j] = fmaf(v2, (float)g2[j], acc[j]);
          acc[j] = fmaf(v3, (float)g3[j], acc[j]);
        }
        qa = qa2; qb = qb2;
        g0 = n0; g1 = n1; g2 = n2; g3 = n3;
      }
    }

    h4 x0v = *(const h4*)(x0h + (size_t)r * D_OUT + c4);
    if (last) {
      float4 o;
      o.x = 0.9f * acc[0] + 0.1f * (float)x0v[0];
      o.y = 0.9f * acc[1] + 0.1f * (float)x0v[1];
      o.z = 0.9f * acc[2] + 0.1f * (float)x0v[2];
      o.w = 0.9f * acc[3] + 0.1f * (float)x0v[3];
      *(float4*)(fout + (size_t)r * D_OUT + c4) = o;
    } else {
      h4 o;
#pragma unroll
      for (int j = 0; j < 4; ++j)
        o[j] = (half_t)(0.9f * acc[j] + 0.1f * (float)x0v[j]);
      *(h4*)(xout + (size_t)r * D_OUT + c4) = o;
    }
  }
}

extern "C" void kernel_launch(void* const* d_in, const int* in_sizes, int n_in,
                              void* d_out, int out_size, void* d_ws, size_t ws_size,
                              hipStream_t stream) {
  const float* F     = (const float*)d_in[0];
  const int*   row   = (const int*)  d_in[1];
  const int*   col   = (const int*)  d_in[2];
  const float* evals = (const float*)d_in[3];
  const float* W1    = (const float*)d_in[4];
  const float* b1    = (const float*)d_in[5];
  const float* W2    = (const float*)d_in[6];
  const float* b2    = (const float*)d_in[7];
  float* out = (float*)d_out;

  // workspace layout (~35.1 MB). ebuck aliases P+Q: ebuck is dead before the
  // first spmm writes P (stream-ordered).
  char* w = (char*)d_ws;
  half_t* x0h    = (half_t*)(w);                //  6,400,000
  half_t* P      = (half_t*)(w +  6400000);     //  6,400,000 (alias ebuck lo)
  half_t* Q      = (half_t*)(w + 12800000);     //  6,400,000 (alias ebuck hi)
  int2*   ebuck  = (int2*)  (w +  6400000);     // 12,800,000
  int2*   epack  = (int2*)  (w + 19200000);     // 15,400,000 (padded CSR)
  int*   row_ptr = (int*)   (w + 34600192);     //    400,128 (N+1)
  int*   bcnt    = (int*)   (w + 35000576);     //      1,024 (zeroed)
  int*   bfill   = (int*)   (w + 35001600);     //      1,024 (zeroed)
  int*   bbase   = (int*)   (w + 35002624);     //      1,024
  int*   pbase   = (int*)   (w + 35003648);     //      1,024
  half_t* W1T    = (half_t*)(w + 35004672);     //     32,768
  half_t* W2T    = (half_t*)(w + 35037440);     //      4,096

  // D0: bhist + weight pack (independent)
  hipMemsetAsync(bcnt, 0, 2048, stream);   // bcnt + bfill
  mix0_kernel<<<640 + 64, 256, 0, stream>>>(row, bcnt, W1, W2, W1T, W2T);

  // D1-D3: CSR chain, each overlapped with an MLP slice (mlp needs W1T: D0 done)
  mix1_kernel<<<1 + MLP_A, 256, 0, stream>>>(
      bcnt, bbase, pbase, F, W1T, b1, W2T, b2, x0h);
  mix2_kernel<<<NCHUNK + MLP_B, 256, 0, stream>>>(
      row, col, evals, bfill, bbase, ebuck, F, W1T, b1, W2T, b2, x0h);
  mix3_kernel<<<NBUCK + MLP_C, 256, 0, stream>>>(
      bbase, pbase, ebuck, epack, row_ptr, F, W1T, b1, W2T, b2, x0h);

  // 10 propagation rounds: x0h -> P -> Q -> ... final writes fp32 d_out
  for (int i = 0; i < NPROP; ++i) {
    const half_t* xin = (i == 0) ? x0h : ((i & 1) ? P : Q);
    half_t* xout = (i & 1) ? Q : P;
    int last = (i == NPROP - 1);
    spmm_kernel<<<SPMM_BLOCKS, 256, 0, stream>>>(
        row_ptr, epack, xin, x0h, xout, out, last);
  }
}